// Round 1
// baseline (199.360 us; speedup 1.0000x reference)
//
#include <hip/hip_runtime.h>

// ProtoNet loss pipeline on MI355X (gfx950).
// C=256 classes, S=5 support, Q=64 queries, D_IN=1024, Z=128.
//
// k_zero    : zero d_out (it is poisoned 0xAA before every call)
// k_xbar    : xbar[c,:] = mean_s xs[c,s,:]                  (256x1024)
// k_gemm_z  : z = [xbar ; xq] @ W   (16640x128) via bf16 MFMA, fp32 out,
//             plus per-row squared norms n2[16640]
// k_gemm_d2 : d2[i,j] = n2[256+i] + n2[j] - 2*dot(zq_i, proto_j)
//             (16384x256) via bf16 MFMA, stored bf16 in ws
// k_reduce  : per class c: acc-count via argmin_j d2, and LOO cosine sum via
//             sum_{q<k} a_q.a_k = 0.5*(||sum_q a_q||^2 - sum_q ||a_q||^2)
//             with t[j] = sum_q D[q][j]/nrm_q  (O(Q*C) per class, no SYRK)

typedef __attribute__((ext_vector_type(8))) short s8v;
typedef __attribute__((ext_vector_type(4))) short s4v;
typedef __attribute__((ext_vector_type(4))) float f32x4;

__device__ __forceinline__ short f2bf(float f) {
  union { float f; unsigned u; } v; v.f = f;
  unsigned r = (v.u + 0x7fffu + ((v.u >> 16) & 1u)) >> 16;   // RNE
  return (short)r;
}
__device__ __forceinline__ float bf2f(unsigned short h) {
  union { unsigned u; float f; } v; v.u = ((unsigned)h) << 16;
  return v.f;
}

__global__ void k_zero(float* __restrict__ out) {
  if (threadIdx.x < 2) out[threadIdx.x] = 0.0f;
}

__global__ void k_xbar(const float* __restrict__ xs, float* __restrict__ xbar) {
  const int c = blockIdx.x;
  const float* b = xs + (size_t)c * 5120;
  for (int e = threadIdx.x; e < 1024; e += 256) {
    float s = b[e] + b[1024 + e] + b[2048 + e] + b[3072 + e] + b[4096 + e];
    xbar[(size_t)c * 1024 + e] = s * 0.2f;
  }
}

// ---------------- z = [xbar ; xq] @ W,  M=16640 N=128 K=1024 ----------------
// Block: 64 rows x 128 cols, 256 threads (4 waves, each wave 16 rows).
// LDS k-stride 40 shorts (mult of 8 for aligned b128 frag reads).
__global__ __launch_bounds__(256) void k_gemm_z(
    const float* __restrict__ xbar, const float* __restrict__ xq,
    const float* __restrict__ W, float* __restrict__ z,
    float* __restrict__ n2) {
  __shared__ short As[64 * 40];    // A[row][k], k-contiguous
  __shared__ short Bs[128 * 40];   // B[n][k],  k-contiguous (W transposed)
  const int tid = threadIdx.x;
  const int rb = blockIdx.x * 64;
  const int w = tid >> 6, lane = tid & 63, ln = lane & 15, q = lane >> 4;
  // block-uniform source select (blocks 0..3 are all-xbar, >=4 all-xq)
  const float* abase = (rb < 256) ? (xbar + (size_t)rb * 1024)
                                  : (xq + (size_t)(rb - 256) * 1024);
  f32x4 acc[8] = {};
  for (int kt = 0; kt < 32; ++kt) {
    // stage A: 64 rows x 32 k  (512 float4)
#pragma unroll
    for (int s = 0; s < 2; ++s) {
      int idx = tid + s * 256;
      int row = idx >> 3, f4 = idx & 7;
      float4 v = *(const float4*)(abase + (size_t)row * 1024 + kt * 32 + f4 * 4);
      s4v sv = { f2bf(v.x), f2bf(v.y), f2bf(v.z), f2bf(v.w) };
      *(s4v*)&As[row * 40 + f4 * 4] = sv;
    }
    // stage B transposed: W rows kt*32..+31, all 128 cols (1024 float4)
#pragma unroll
    for (int s = 0; s < 4; ++s) {
      int idx = tid + s * 256;
      int k = idx >> 5, n4 = idx & 31;
      float4 v = *(const float4*)(W + (size_t)(kt * 32 + k) * 128 + n4 * 4);
      Bs[(n4 * 4 + 0) * 40 + k] = f2bf(v.x);
      Bs[(n4 * 4 + 1) * 40 + k] = f2bf(v.y);
      Bs[(n4 * 4 + 2) * 40 + k] = f2bf(v.z);
      Bs[(n4 * 4 + 3) * 40 + k] = f2bf(v.w);
    }
    __syncthreads();
    s8v af = *(const s8v*)&As[(w * 16 + ln) * 40 + q * 8];
#pragma unroll
    for (int t = 0; t < 8; ++t) {
      s8v bf = *(const s8v*)&Bs[(t * 16 + ln) * 40 + q * 8];
      acc[t] = __builtin_amdgcn_mfma_f32_16x16x32_bf16(af, bf, acc[t], 0, 0, 0);
    }
    __syncthreads();
  }
  // epilogue: store fp32 z + per-row squared norms
#pragma unroll
  for (int p = 0; p < 4; ++p) {
    int grow = rb + w * 16 + q * 4 + p;   // C/D: row = quad*4 + reg
    float sp = 0.0f;
#pragma unroll
    for (int t = 0; t < 8; ++t) {
      float v = acc[t][p];                // col = t*16 + ln
      z[(size_t)grow * 128 + t * 16 + ln] = v;
      sp += v * v;
    }
    sp += __shfl_xor(sp, 1);
    sp += __shfl_xor(sp, 2);
    sp += __shfl_xor(sp, 4);
    sp += __shfl_xor(sp, 8);
    if (ln == 0) n2[grow] = sp;
  }
}

// ------------- d2 GEMM: M=16384 (queries) N=256 (protos) K=128 -------------
// Block: 64 query rows x 128 proto cols, grid 512 = 256 row-tiles x 2 col-tiles.
__global__ __launch_bounds__(256) void k_gemm_d2(
    const float* __restrict__ z, const float* __restrict__ n2,
    unsigned short* __restrict__ d2b) {
  __shared__ short As[64 * 136];
  __shared__ short Bs[128 * 136];
  const int tid = threadIdx.x;
  const int rbq = (blockIdx.x >> 1) * 64;
  const int nb = (blockIdx.x & 1) * 128;
  const int w = tid >> 6, lane = tid & 63, ln = lane & 15, q = lane >> 4;
  const float* zq = z + (size_t)(256 + rbq) * 128;
  const float* zp = z + (size_t)nb * 128;
#pragma unroll
  for (int s = 0; s < 8; ++s) {           // A: 64x128
    int idx = tid + s * 256;
    int row = idx >> 5, f4 = idx & 31;
    float4 v = *(const float4*)(zq + (size_t)row * 128 + f4 * 4);
    s4v sv = { f2bf(v.x), f2bf(v.y), f2bf(v.z), f2bf(v.w) };
    *(s4v*)&As[row * 136 + f4 * 4] = sv;
  }
#pragma unroll
  for (int s = 0; s < 16; ++s) {          // B: proto rows, no transpose needed
    int idx = tid + s * 256;
    int row = idx >> 5, f4 = idx & 31;
    float4 v = *(const float4*)(zp + (size_t)row * 128 + f4 * 4);
    s4v sv = { f2bf(v.x), f2bf(v.y), f2bf(v.z), f2bf(v.w) };
    *(s4v*)&Bs[row * 136 + f4 * 4] = sv;
  }
  __syncthreads();
  f32x4 acc[8] = {};
#pragma unroll
  for (int kk = 0; kk < 4; ++kk) {
    s8v af = *(const s8v*)&As[(w * 16 + ln) * 136 + kk * 32 + q * 8];
#pragma unroll
    for (int t = 0; t < 8; ++t) {
      s8v bf = *(const s8v*)&Bs[(t * 16 + ln) * 136 + kk * 32 + q * 8];
      acc[t] = __builtin_amdgcn_mfma_f32_16x16x32_bf16(af, bf, acc[t], 0, 0, 0);
    }
  }
#pragma unroll
  for (int p = 0; p < 4; ++p) {
    int qr = rbq + w * 16 + q * 4 + p;
    float qn = n2[256 + qr];
#pragma unroll
    for (int t = 0; t < 8; ++t) {
      int pc = nb + t * 16 + ln;
      float v = qn + n2[pc] - 2.0f * acc[t][p];
      d2b[(size_t)qr * 256 + pc] = (unsigned short)f2bf(v);
    }
  }
}

// --------- per-class reduction: acc count + LOO cosine pair sum ---------
__global__ __launch_bounds__(256) void k_reduce(
    const unsigned short* __restrict__ d2b, float* __restrict__ out) {
  __shared__ unsigned short D[64 * 258];  // stride 258: conflict-free scans
  __shared__ float rv[256];
  __shared__ int   ri[256];
  __shared__ float rss[256];
  __shared__ float invn[64];
  __shared__ float sred[4];
  __shared__ float s_tc, s_aq2, s_corr;
  const int tid = threadIdx.x;
  const int c = blockIdx.x;
  const unsigned short* src = d2b + (size_t)c * 64 * 256;
  // load: thread tid owns column j=tid, rows stream (coalesced across lanes)
  for (int s = 0; s < 64; ++s) D[s * 258 + tid] = src[s * 256 + tid];
  __syncthreads();
  // per-row stats (min+idx, sum of squares), wave w handles j-quarter w*64..
  {
    const int w = tid >> 6, q = tid & 63, jb = (tid >> 6) * 64;
    float mn = 3.4e38f; int mi = 0; float ss = 0.0f;
    for (int jj = 0; jj < 64; ++jj) {
      int j = jb + jj;
      float f = bf2f(D[q * 258 + j]);
      ss += f * f;
      if (f < mn) { mn = f; mi = j; }
    }
    rv[tid] = mn; ri[tid] = mi; rss[tid] = ss;
    (void)w;
  }
  __syncthreads();
  if (tid < 64) {   // combine quarters; ascending h + strict < => first-occurrence
    float bm = rv[tid]; int bi = ri[tid]; float ss = rss[tid];
    for (int h = 1; h < 4; ++h) {
      float v = rv[h * 64 + tid];
      ss += rss[h * 64 + tid];
      if (v < bm) { bm = v; bi = ri[h * 64 + tid]; }
    }
    float col = bf2f(D[tid * 258 + c]);
    float loo2 = fmaxf(ss - col * col, 0.0f);
    float nrm = fmaxf(sqrtf(loo2), 1e-8f);
    float inv = 1.0f / nrm;
    invn[tid] = inv;
    float aq2 = loo2 * inv * inv;          // ||a_q||^2
    float corr = (bi == c) ? 1.0f : 0.0f;
    for (int m = 1; m < 64; m <<= 1) {
      aq2 += __shfl_xor(aq2, m);
      corr += __shfl_xor(corr, m);
    }
    if (tid == 0) { s_aq2 = aq2; s_corr = corr; }
  }
  __syncthreads();
  // t[j] = sum_q D[q][j] * invn[q]
  float t = 0.0f;
  for (int qq = 0; qq < 64; ++qq) t += bf2f(D[qq * 258 + tid]) * invn[qq];
  if (tid == c) s_tc = t;
  float t2 = t * t;
  for (int m = 1; m < 64; m <<= 1) t2 += __shfl_xor(t2, m);
  if ((tid & 63) == 0) sred[tid >> 6] = t2;
  __syncthreads();
  if (tid == 0) {
    float S2 = sred[0] + sred[1] + sred[2] + sred[3];
    float bs = 0.5f * (S2 - s_tc * s_tc - s_aq2);  // sum_{q<k} sim
    atomicAdd(&out[0], bs * (1.0f / 516096.0f));   // / (C * Q*(Q-1)/2)
    atomicAdd(&out[1], s_corr * (1.0f / 16384.0f)); // / (C*Q)
  }
}

extern "C" void kernel_launch(void* const* d_in, const int* in_sizes, int n_in,
                              void* d_out, int out_size, void* d_ws, size_t ws_size,
                              hipStream_t stream) {
  const float* xs = (const float*)d_in[0];   // 256*5*1024
  const float* xq = (const float*)d_in[1];   // 256*64*1024
  const float* W  = (const float*)d_in[2];   // 1024*128
  float* out = (float*)d_out;

  float* ws = (float*)d_ws;
  float* xbar = ws;                                   // 262144 floats
  float* z    = ws + 262144;                          // 16640*128 floats
  float* n2   = z + (size_t)16640 * 128;              // 16640 floats
  unsigned short* d2b = (unsigned short*)(n2 + 16640);// 16384*256 bf16 (~8.4MB)

  k_zero<<<dim3(1), dim3(64), 0, stream>>>(out);
  k_xbar<<<dim3(256), dim3(256), 0, stream>>>(xs, xbar);
  k_gemm_z<<<dim3(260), dim3(256), 0, stream>>>(xbar, xq, W, z, n2);
  k_gemm_d2<<<dim3(512), dim3(256), 0, stream>>>(z, n2, d2b);
  k_reduce<<<dim3(256), dim3(256), 0, stream>>>(d2b, out);
}

// Round 2
// 160.677 us; speedup vs baseline: 1.2408x; 1.2408x over previous
//
#include <hip/hip_runtime.h>

// ProtoNet loss pipeline on MI355X (gfx950) — round 2: LDS-free GEMMs.
// C=256 classes, S=5 support, Q=64 queries, D_IN=1024, Z=128.
//
// k_zero   : zero d_out
// k_xbar   : xbar[c,:] = mean_s xs[c,s,:]             (256x1024 fp32)
// k_wt     : Wt[n][k]  = bf16(W[k][n])                (128x1024 bf16, LDS transpose)
// k_gemm_z : zb = bf16([xbar;xq] @ W) + n2 row norms. Barrier-free: one wave
//            owns 16 rows x 128 cols; A frags direct fp32 global loads ->
//            in-register bf16; B frags direct 16B loads from Wt (L2-hot).
// k_d2red  : per class c (one block): d2 tile 64x256 via MFMA from zb,
//            fp32 Dt[j][q] in LDS (stride 65, conflict-free both ways),
//            then argmin-acc + LOO-cosine via
//            sum_{q<k} a_q.a_k = 0.5*(||sum_q a_q||^2 - sum ||a_q||^2).

typedef __attribute__((ext_vector_type(8))) short s8v;
typedef __attribute__((ext_vector_type(4))) float f32x4;

__device__ __forceinline__ short f2bf(float f) {
  union { float f; unsigned u; } v; v.f = f;
  unsigned r = (v.u + 0x7fffu + ((v.u >> 16) & 1u)) >> 16;   // RNE
  return (short)r;
}

__global__ void k_zero(float* __restrict__ out) {
  if (threadIdx.x < 2) out[threadIdx.x] = 0.0f;
}

__global__ void k_xbar(const float* __restrict__ xs, float* __restrict__ xbar) {
  const int c = blockIdx.x;
  const float* b = xs + (size_t)c * 5120;
  for (int e = threadIdx.x; e < 1024; e += 256) {
    float s = b[e] + b[1024 + e] + b[2048 + e] + b[3072 + e] + b[4096 + e];
    xbar[(size_t)c * 1024 + e] = s * 0.2f;
  }
}

// W [k=1024][n=128] fp32  ->  Wt [n=128][k=1024] bf16. Block: 64 k-rows.
__global__ __launch_bounds__(256) void k_wt(const float* __restrict__ W,
                                            unsigned short* __restrict__ Wt) {
  __shared__ unsigned short T[128 * 68];
  const int tid = threadIdx.x;
  const int kb = blockIdx.x * 64;
#pragma unroll
  for (int s = 0; s < 8; ++s) {          // 2048 float4 = 64 k x 32 n4
    int idx = tid + s * 256;
    int kr = idx >> 5, n4 = idx & 31;
    float4 v = *(const float4*)(W + (size_t)(kb + kr) * 128 + n4 * 4);
    T[(n4 * 4 + 0) * 68 + kr] = (unsigned short)f2bf(v.x);
    T[(n4 * 4 + 1) * 68 + kr] = (unsigned short)f2bf(v.y);
    T[(n4 * 4 + 2) * 68 + kr] = (unsigned short)f2bf(v.z);
    T[(n4 * 4 + 3) * 68 + kr] = (unsigned short)f2bf(v.w);
  }
  __syncthreads();
#pragma unroll
  for (int s = 0; s < 8; ++s) {          // 2048 ushort4 = 128 n x 16 k4
    int idx = tid + s * 256;
    int n = idx >> 4, k4 = idx & 15;
    ushort4 o;
    o.x = T[n * 68 + k4 * 4 + 0];
    o.y = T[n * 68 + k4 * 4 + 1];
    o.z = T[n * 68 + k4 * 4 + 2];
    o.w = T[n * 68 + k4 * 4 + 3];
    *(ushort4*)(Wt + (size_t)n * 1024 + kb + k4 * 4) = o;
  }
}

// ---------------- z = [xbar ; xq] @ W,  M=16640 N=128 K=1024 ----------------
// One wave per 16 rows; no LDS, no barriers. 1040 blocks x 64 threads.
__global__ __launch_bounds__(64) void k_gemm_z(
    const float* __restrict__ xbar, const float* __restrict__ xq,
    const unsigned short* __restrict__ Wt,
    unsigned short* __restrict__ zb, float* __restrict__ n2) {
  const int rb = blockIdx.x * 16;
  const int lane = threadIdx.x & 63, ln = lane & 15, q = lane >> 4;
  const float* abase = (rb < 256) ? (xbar + (size_t)rb * 1024)
                                  : (xq + (size_t)(rb - 256) * 1024);
  const float* arow = abase + (size_t)ln * 1024 + q * 8;  // lane's A base
  f32x4 acc[8] = {};
  float4 a0 = *(const float4*)(arow);
  float4 a1 = *(const float4*)(arow + 4);
  for (int kt = 0; kt < 32; ++kt) {
    float4 p0, p1;
    if (kt < 31) {
      p0 = *(const float4*)(arow + (kt + 1) * 32);
      p1 = *(const float4*)(arow + (kt + 1) * 32 + 4);
    }
    s8v af = { f2bf(a0.x), f2bf(a0.y), f2bf(a0.z), f2bf(a0.w),
               f2bf(a1.x), f2bf(a1.y), f2bf(a1.z), f2bf(a1.w) };
#pragma unroll
    for (int t = 0; t < 8; ++t) {
      s8v bf = *(const s8v*)(Wt + (size_t)(t * 16 + ln) * 1024 + kt * 32 + q * 8);
      acc[t] = __builtin_amdgcn_mfma_f32_16x16x32_bf16(af, bf, acc[t], 0, 0, 0);
    }
    a0 = p0; a1 = p1;
  }
#pragma unroll
  for (int p = 0; p < 4; ++p) {
    int grow = rb + q * 4 + p;            // C/D: row = quad*4 + reg
    float sp = 0.0f;
#pragma unroll
    for (int t = 0; t < 8; ++t) {
      float v = acc[t][p];                // col = t*16 + ln
      zb[(size_t)grow * 128 + t * 16 + ln] = (unsigned short)f2bf(v);
      sp += v * v;
    }
    sp += __shfl_xor(sp, 1);
    sp += __shfl_xor(sp, 2);
    sp += __shfl_xor(sp, 4);
    sp += __shfl_xor(sp, 8);
    if (ln == 0) n2[grow] = sp;
  }
}

// --------- fused d2 GEMM (64 queries x 256 protos) + per-class reduce ---------
__global__ __launch_bounds__(256) void k_d2red(
    const unsigned short* __restrict__ zb, const float* __restrict__ n2,
    float* __restrict__ out) {
  __shared__ float Dt[256 * 65];          // Dt[j][q], stride 65 (bank-free)
  __shared__ float rv[256];
  __shared__ int   ri[256];
  __shared__ float rss[256];
  __shared__ float invn[64];
  __shared__ float sred[4];
  __shared__ float s_tc, s_aq2, s_corr;
  const int tid = threadIdx.x;
  const int c = blockIdx.x;
  const int w = tid >> 6, lane = tid & 63, ln = lane & 15, qd = lane >> 4;

  // d2 tile via MFMA: wave w handles query rows c*64 + w*16 .. +15
  f32x4 acc[16] = {};
  const unsigned short* Az = zb + (size_t)(256 + c * 64 + w * 16 + ln) * 128;
#pragma unroll
  for (int kt = 0; kt < 4; ++kt) {
    s8v af = *(const s8v*)(Az + kt * 32 + qd * 8);
#pragma unroll
    for (int t = 0; t < 16; ++t) {
      s8v bf = *(const s8v*)(zb + (size_t)(t * 16 + ln) * 128 + kt * 32 + qd * 8);
      acc[t] = __builtin_amdgcn_mfma_f32_16x16x32_bf16(af, bf, acc[t], 0, 0, 0);
    }
  }
#pragma unroll
  for (int p = 0; p < 4; ++p) {
    int qloc = w * 16 + qd * 4 + p;
    float qn = n2[256 + c * 64 + qloc];
#pragma unroll
    for (int t = 0; t < 16; ++t) {
      int j = t * 16 + ln;
      Dt[j * 65 + qloc] = qn + n2[j] - 2.0f * acc[t][p];
    }
  }
  __syncthreads();

  // per-row (query) stats: thread tid handles row q=tid&63, j-quarter (tid>>6)
  {
    const int q = tid & 63, jb = (tid >> 6) * 64;
    float mn = 3.4e38f; int mi = 0; float ss = 0.0f;
    for (int jj = 0; jj < 64; ++jj) {
      int j = jb + jj;
      float f = Dt[j * 65 + q];
      ss += f * f;
      if (f < mn) { mn = f; mi = j; }
    }
    rv[tid] = mn; ri[tid] = mi; rss[tid] = ss;
  }
  __syncthreads();
  if (tid < 64) {   // combine quarters; ascending h + strict < => first-occurrence
    float bm = rv[tid]; int bi = ri[tid]; float ss = rss[tid];
    for (int h = 1; h < 4; ++h) {
      float v = rv[h * 64 + tid];
      ss += rss[h * 64 + tid];
      if (v < bm) { bm = v; bi = ri[h * 64 + tid]; }
    }
    float col = Dt[c * 65 + tid];
    float loo2 = fmaxf(ss - col * col, 0.0f);
    float nrm = fmaxf(sqrtf(loo2), 1e-8f);
    float inv = 1.0f / nrm;
    invn[tid] = inv;
    float aq2 = loo2 * inv * inv;          // ||a_q||^2
    float corr = (bi == c) ? 1.0f : 0.0f;
    for (int m = 1; m < 64; m <<= 1) {
      aq2 += __shfl_xor(aq2, m);
      corr += __shfl_xor(corr, m);
    }
    if (tid == 0) { s_aq2 = aq2; s_corr = corr; }
  }
  __syncthreads();
  // t[j] = sum_q D[q][j] * invn[q]; thread tid = j
  float t = 0.0f;
  for (int qq = 0; qq < 64; ++qq) t += Dt[tid * 65 + qq] * invn[qq];
  if (tid == c) s_tc = t;
  float t2 = t * t;
  for (int m = 1; m < 64; m <<= 1) t2 += __shfl_xor(t2, m);
  if ((tid & 63) == 0) sred[tid >> 6] = t2;
  __syncthreads();
  if (tid == 0) {
    float S2 = sred[0] + sred[1] + sred[2] + sred[3];
    float bs = 0.5f * (S2 - s_tc * s_tc - s_aq2);   // sum_{q<k} sim
    atomicAdd(&out[0], bs * (1.0f / 516096.0f));    // / (C * Q*(Q-1)/2)
    atomicAdd(&out[1], s_corr * (1.0f / 16384.0f)); // / (C*Q)
  }
}

extern "C" void kernel_launch(void* const* d_in, const int* in_sizes, int n_in,
                              void* d_out, int out_size, void* d_ws, size_t ws_size,
                              hipStream_t stream) {
  const float* xs = (const float*)d_in[0];   // 256*5*1024
  const float* xq = (const float*)d_in[1];   // 256*64*1024
  const float* W  = (const float*)d_in[2];   // 1024*128
  float* out = (float*)d_out;

  float* ws = (float*)d_ws;
  float* xbar = ws;                                    // 262144 fp32 (1 MB)
  unsigned short* Wt = (unsigned short*)(xbar + 262144);          // 128K bf16
  unsigned short* zb = Wt + 131072;                               // 16640*128 bf16
  float* n2 = (float*)(zb + (size_t)16640 * 128);                 // 16640 fp32

  k_zero<<<dim3(1), dim3(64), 0, stream>>>(out);
  k_xbar<<<dim3(256), dim3(256), 0, stream>>>(xs, xbar);
  k_wt<<<dim3(16), dim3(256), 0, stream>>>(W, Wt);
  k_gemm_z<<<dim3(1040), dim3(64), 0, stream>>>(xbar, xq, Wt, zb, n2);
  k_d2red<<<dim3(256), dim3(256), 0, stream>>>(zb, n2, out);
}

// Round 3
// 152.814 us; speedup vs baseline: 1.3046x; 1.0515x over previous
//
#include <hip/hip_runtime.h>

// ProtoNet loss pipeline on MI355X (gfx950) — round 3.
// C=256 classes, S=5 support, Q=64 queries, D_IN=1024, Z=128.
//
// Round-3 changes (theory: VGPR caps from default launch_bounds serialized
// all memory-level parallelism):
//  - k_gemm_z: __launch_bounds__(64,1) (512-VGPR budget), explicit
//    double-buffered B fragments + A prefetch distance 2. Work-limited to
//    1 wave/SIMD, so per-wave ILP is the only latency hiding — needs regs.
//  - k_d2red: __launch_bounds__(256,1) — acc[16] is 64 VGPRs; the old
//    implicit 64-VGPR cap forced scratch spills.
//  - k_prep fuses zero + xbar + W-transpose (fewer launches).

typedef __attribute__((ext_vector_type(8))) short s8v;
typedef __attribute__((ext_vector_type(4))) float f32x4;

__device__ __forceinline__ short f2bf(float f) {
  union { float f; unsigned u; } v; v.f = f;
  unsigned r = (v.u + 0x7fffu + ((v.u >> 16) & 1u)) >> 16;   // RNE
  return (short)r;
}

// blocks 0..255: xbar[c,:] = mean_s xs[c,s,:]; block 0 also zeroes out[0..1].
// blocks 256..271: Wt[n][k] = bf16(W[k][n]) via LDS transpose (64 k-rows each).
__global__ __launch_bounds__(256) void k_prep(
    const float* __restrict__ xs, const float* __restrict__ W,
    float* __restrict__ xbar, unsigned short* __restrict__ Wt,
    float* __restrict__ out) {
  __shared__ unsigned short T[128 * 68];
  const int tid = threadIdx.x;
  if (blockIdx.x < 256) {
    const int c = blockIdx.x;
    if (c == 0 && tid < 2) out[tid] = 0.0f;
    const float* b = xs + (size_t)c * 5120;
    for (int e = tid; e < 1024; e += 256) {
      float s = b[e] + b[1024 + e] + b[2048 + e] + b[3072 + e] + b[4096 + e];
      xbar[(size_t)c * 1024 + e] = s * 0.2f;
    }
  } else {
    const int kb = (blockIdx.x - 256) * 64;
#pragma unroll
    for (int s = 0; s < 8; ++s) {          // 2048 float4 = 64 k x 32 n4
      int idx = tid + s * 256;
      int kr = idx >> 5, n4 = idx & 31;
      float4 v = *(const float4*)(W + (size_t)(kb + kr) * 128 + n4 * 4);
      T[(n4 * 4 + 0) * 68 + kr] = (unsigned short)f2bf(v.x);
      T[(n4 * 4 + 1) * 68 + kr] = (unsigned short)f2bf(v.y);
      T[(n4 * 4 + 2) * 68 + kr] = (unsigned short)f2bf(v.z);
      T[(n4 * 4 + 3) * 68 + kr] = (unsigned short)f2bf(v.w);
    }
    __syncthreads();
#pragma unroll
    for (int s = 0; s < 8; ++s) {          // 2048 ushort4 = 128 n x 16 k4
      int idx = tid + s * 256;
      int n = idx >> 4, k4 = idx & 15;
      ushort4 o;
      o.x = T[n * 68 + k4 * 4 + 0];
      o.y = T[n * 68 + k4 * 4 + 1];
      o.z = T[n * 68 + k4 * 4 + 2];
      o.w = T[n * 68 + k4 * 4 + 3];
      *(ushort4*)(Wt + (size_t)n * 1024 + kb + k4 * 4) = o;
    }
  }
}

// ---------------- z = [xbar ; xq] @ W,  M=16640 N=128 K=1024 ----------------
// One wave per 16 rows; no LDS, no barriers. 1040 blocks x 64 threads.
// B frags double-buffered (2x8 s8v = 64 VGPRs), A prefetch distance 2.
__global__ __launch_bounds__(64, 1) void k_gemm_z(
    const float* __restrict__ xbar, const float* __restrict__ xq,
    const unsigned short* __restrict__ Wt,
    unsigned short* __restrict__ zb, float* __restrict__ n2) {
  const int rb = blockIdx.x * 16;
  const int lane = threadIdx.x & 63, ln = lane & 15, q = lane >> 4;
  const float* abase = (rb < 256) ? (xbar + (size_t)rb * 1024)
                                  : (xq + (size_t)(rb - 256) * 1024);
  const float* arow = abase + (size_t)ln * 1024 + q * 8;
  const unsigned short* brow = Wt + (size_t)ln * 1024 + q * 8;
  f32x4 acc[8] = {};
  float4 a0[2], a1[2];
  s8v bfr[2][8];
  a0[0] = *(const float4*)(arow + 0);
  a1[0] = *(const float4*)(arow + 4);
  a0[1] = *(const float4*)(arow + 32);
  a1[1] = *(const float4*)(arow + 36);
#pragma unroll
  for (int t = 0; t < 8; ++t)
    bfr[0][t] = *(const s8v*)(brow + (size_t)t * 16 * 1024);
#pragma unroll
  for (int kt = 0; kt < 32; ++kt) {
    const int cur = kt & 1;
    if (kt < 31) {
#pragma unroll
      for (int t = 0; t < 8; ++t)
        bfr[cur ^ 1][t] =
            *(const s8v*)(brow + (size_t)t * 16 * 1024 + (kt + 1) * 32);
    }
    s8v af = { f2bf(a0[cur].x), f2bf(a0[cur].y), f2bf(a0[cur].z), f2bf(a0[cur].w),
               f2bf(a1[cur].x), f2bf(a1[cur].y), f2bf(a1[cur].z), f2bf(a1[cur].w) };
    if (kt < 30) {
      a0[cur] = *(const float4*)(arow + (kt + 2) * 32);
      a1[cur] = *(const float4*)(arow + (kt + 2) * 32 + 4);
    }
#pragma unroll
    for (int t = 0; t < 8; ++t)
      acc[t] = __builtin_amdgcn_mfma_f32_16x16x32_bf16(af, bfr[cur][t], acc[t], 0, 0, 0);
  }
#pragma unroll
  for (int p = 0; p < 4; ++p) {
    int grow = rb + q * 4 + p;            // C/D: row = quad*4 + reg
    float sp = 0.0f;
#pragma unroll
    for (int t = 0; t < 8; ++t) {
      float v = acc[t][p];                // col = t*16 + ln
      zb[(size_t)grow * 128 + t * 16 + ln] = (unsigned short)f2bf(v);
      sp += v * v;
    }
    sp += __shfl_xor(sp, 1);
    sp += __shfl_xor(sp, 2);
    sp += __shfl_xor(sp, 4);
    sp += __shfl_xor(sp, 8);
    if (ln == 0) n2[grow] = sp;
  }
}

// --------- fused d2 GEMM (64 queries x 256 protos) + per-class reduce ---------
__global__ __launch_bounds__(256, 1) void k_d2red(
    const unsigned short* __restrict__ zb, const float* __restrict__ n2,
    float* __restrict__ out) {
  __shared__ float Dt[256 * 65];          // Dt[j][q], stride 65 (bank-free)
  __shared__ float rv[256];
  __shared__ int   ri[256];
  __shared__ float rss[256];
  __shared__ float invn[64];
  __shared__ float sred[4];
  __shared__ float s_tc, s_aq2, s_corr;
  const int tid = threadIdx.x;
  const int c = blockIdx.x;
  const int w = tid >> 6, lane = tid & 63, ln = lane & 15, qd = lane >> 4;

  // d2 tile via MFMA: wave w handles query rows c*64 + w*16 .. +15
  f32x4 acc[16] = {};
  const unsigned short* Az = zb + (size_t)(256 + c * 64 + w * 16 + ln) * 128;
#pragma unroll
  for (int kt = 0; kt < 4; ++kt) {
    s8v af = *(const s8v*)(Az + kt * 32 + qd * 8);
#pragma unroll
    for (int t = 0; t < 16; ++t) {
      s8v bf = *(const s8v*)(zb + (size_t)(t * 16 + ln) * 128 + kt * 32 + qd * 8);
      acc[t] = __builtin_amdgcn_mfma_f32_16x16x32_bf16(af, bf, acc[t], 0, 0, 0);
    }
  }
#pragma unroll
  for (int p = 0; p < 4; ++p) {
    int qloc = w * 16 + qd * 4 + p;
    float qn = n2[256 + c * 64 + qloc];
#pragma unroll
    for (int t = 0; t < 16; ++t) {
      int j = t * 16 + ln;
      Dt[j * 65 + qloc] = qn + n2[j] - 2.0f * acc[t][p];
    }
  }
  __syncthreads();

  // per-row (query) stats: thread tid handles row q=tid&63, j-quarter (tid>>6)
  {
    const int q = tid & 63, jb = (tid >> 6) * 64;
    float mn = 3.4e38f; int mi = 0; float ss = 0.0f;
    for (int jj = 0; jj < 64; ++jj) {
      int j = jb + jj;
      float f = Dt[j * 65 + q];
      ss += f * f;
      if (f < mn) { mn = f; mi = j; }
    }
    rv[tid] = mn; ri[tid] = mi; rss[tid] = ss;
  }
  __syncthreads();
  if (tid < 64) {   // combine quarters; ascending h + strict < => first-occurrence
    float bm = rv[tid]; int bi = ri[tid]; float ss = rss[tid];
    for (int h = 1; h < 4; ++h) {
      float v = rv[h * 64 + tid];
      ss += rss[h * 64 + tid];
      if (v < bm) { bm = v; bi = ri[h * 64 + tid]; }
    }
    float col = Dt[c * 65 + tid];
    float loo2 = fmaxf(ss - col * col, 0.0f);
    float nrm = fmaxf(sqrtf(loo2), 1e-8f);
    float inv = 1.0f / nrm;
    invn[tid] = inv;
    float aq2 = loo2 * inv * inv;          // ||a_q||^2
    float corr = (bi == c) ? 1.0f : 0.0f;
    for (int m = 1; m < 64; m <<= 1) {
      aq2 += __shfl_xor(aq2, m);
      corr += __shfl_xor(corr, m);
    }
    if (tid == 0) { s_aq2 = aq2; s_corr = corr; }
  }
  __syncthreads();
  // t[j] = sum_q D[q][j] * invn[q]; thread tid = j
  float t = 0.0f;
  for (int qq = 0; qq < 64; ++qq) t += Dt[tid * 65 + qq] * invn[qq];
  if (tid == c) s_tc = t;
  float t2 = t * t;
  for (int m = 1; m < 64; m <<= 1) t2 += __shfl_xor(t2, m);
  if ((tid & 63) == 0) sred[tid >> 6] = t2;
  __syncthreads();
  if (tid == 0) {
    float S2 = sred[0] + sred[1] + sred[2] + sred[3];
    float bs = 0.5f * (S2 - s_tc * s_tc - s_aq2);   // sum_{q<k} sim
    atomicAdd(&out[0], bs * (1.0f / 516096.0f));    // / (C * Q*(Q-1)/2)
    atomicAdd(&out[1], s_corr * (1.0f / 16384.0f)); // / (C*Q)
  }
}

extern "C" void kernel_launch(void* const* d_in, const int* in_sizes, int n_in,
                              void* d_out, int out_size, void* d_ws, size_t ws_size,
                              hipStream_t stream) {
  const float* xs = (const float*)d_in[0];   // 256*5*1024
  const float* xq = (const float*)d_in[1];   // 256*64*1024
  const float* W  = (const float*)d_in[2];   // 1024*128
  float* out = (float*)d_out;

  float* ws = (float*)d_ws;
  float* xbar = ws;                                    // 262144 fp32 (1 MB)
  unsigned short* Wt = (unsigned short*)(xbar + 262144);          // 128K bf16
  unsigned short* zb = Wt + 131072;                               // 16640*128 bf16
  float* n2 = (float*)(zb + (size_t)16640 * 128);                 // 16640 fp32

  k_prep<<<dim3(272), dim3(256), 0, stream>>>(xs, W, xbar, Wt, out);
  k_gemm_z<<<dim3(1040), dim3(64), 0, stream>>>(xbar, xq, Wt, zb, n2);
  k_d2red<<<dim3(256), dim3(256), 0, stream>>>(zb, n2, out);
}

// Round 4
// 144.594 us; speedup vs baseline: 1.3788x; 1.0568x over previous
//
#include <hip/hip_runtime.h>

// ProtoNet loss pipeline on MI355X (gfx950) — round 4.
// C=256 classes, S=5 support, Q=64 queries, D_IN=1024, Z=128.
//
// Round-4 change: k_gemm_z restructured. Rounds 2/3 were latency-serialized
// (406 cyc/load, VGPR capped at 60 by the scheduler's occupancy heuristic).
// New structure: 256-thread blocks, 64 rows x 128 cols, B tile staged through
// double-buffered LDS (8 KB/tile, fragment-major: ds_write_b128/ds_read_b128
// both at lane*16 -> conflict-free), staging loads issued one tile ahead so
// the only per-tile wait is one barrier. A = direct fp32 loads, distance-2
// register prefetch. amdgpu_waves_per_eu(1,2) for a 256-VGPR budget.
// k_d2red / k_prep unchanged (control; top-5 will expose their true cost).

typedef __attribute__((ext_vector_type(8))) short s8v;
typedef __attribute__((ext_vector_type(4))) float f32x4;

__device__ __forceinline__ short f2bf(float f) {
  union { float f; unsigned u; } v; v.f = f;
  unsigned r = (v.u + 0x7fffu + ((v.u >> 16) & 1u)) >> 16;   // RNE
  return (short)r;
}

// blocks 0..255: xbar[c,:] = mean_s xs[c,s,:]; block 0 also zeroes out[0..1].
// blocks 256..271: Wt[n][k] = bf16(W[k][n]) via LDS transpose (64 k-rows each).
__global__ __launch_bounds__(256) void k_prep(
    const float* __restrict__ xs, const float* __restrict__ W,
    float* __restrict__ xbar, unsigned short* __restrict__ Wt,
    float* __restrict__ out) {
  __shared__ unsigned short T[128 * 68];
  const int tid = threadIdx.x;
  if (blockIdx.x < 256) {
    const int c = blockIdx.x;
    if (c == 0 && tid < 2) out[tid] = 0.0f;
    const float* b = xs + (size_t)c * 5120;
    for (int e = tid; e < 1024; e += 256) {
      float s = b[e] + b[1024 + e] + b[2048 + e] + b[3072 + e] + b[4096 + e];
      xbar[(size_t)c * 1024 + e] = s * 0.2f;
    }
  } else {
    const int kb = (blockIdx.x - 256) * 64;
#pragma unroll
    for (int s = 0; s < 8; ++s) {          // 2048 float4 = 64 k x 32 n4
      int idx = tid + s * 256;
      int kr = idx >> 5, n4 = idx & 31;
      float4 v = *(const float4*)(W + (size_t)(kb + kr) * 128 + n4 * 4);
      T[(n4 * 4 + 0) * 68 + kr] = (unsigned short)f2bf(v.x);
      T[(n4 * 4 + 1) * 68 + kr] = (unsigned short)f2bf(v.y);
      T[(n4 * 4 + 2) * 68 + kr] = (unsigned short)f2bf(v.z);
      T[(n4 * 4 + 3) * 68 + kr] = (unsigned short)f2bf(v.w);
    }
    __syncthreads();
#pragma unroll
    for (int s = 0; s < 8; ++s) {          // 2048 ushort4 = 128 n x 16 k4
      int idx = tid + s * 256;
      int n = idx >> 4, k4 = idx & 15;
      ushort4 o;
      o.x = T[n * 68 + k4 * 4 + 0];
      o.y = T[n * 68 + k4 * 4 + 1];
      o.z = T[n * 68 + k4 * 4 + 2];
      o.w = T[n * 68 + k4 * 4 + 3];
      *(ushort4*)(Wt + (size_t)n * 1024 + kb + k4 * 4) = o;
    }
  }
}

// ---------------- z = [xbar ; xq] @ W,  M=16640 N=128 K=1024 ----------------
// 260 blocks x 256 threads. Block = 64 rows x 128 cols; wave w owns rows
// w*16..+15 (all 128 cols). B double-buffered in LDS, fragment-major.
__global__ __launch_bounds__(256)
__attribute__((amdgpu_waves_per_eu(1, 2))) void k_gemm_z(
    const float* __restrict__ xbar, const float* __restrict__ xq,
    const unsigned short* __restrict__ Wt,
    unsigned short* __restrict__ zb, float* __restrict__ n2) {
  __shared__ short Bs[2][4096];           // 2 x 8 KB
  const int tid = threadIdx.x;
  const int w = tid >> 6, l = tid & 63, ln = l & 15, qd = l >> 4;
  const int rb = blockIdx.x * 64;
  const float* abase = (rb < 256) ? (xbar + (size_t)rb * 1024)
                                  : (xq + (size_t)(rb - 256) * 1024);
  const float* arow = abase + (size_t)(w * 16 + ln) * 1024 + qd * 8;
  // B staging: thread stages t-groups tg0=2w, tg1=2w+1; chunk = its own lane.
  const int tg0 = 2 * w, tg1 = 2 * w + 1;
  const unsigned short* bsrc0 = Wt + (size_t)(tg0 * 16 + ln) * 1024 + qd * 8;
  const unsigned short* bsrc1 = Wt + (size_t)(tg1 * 16 + ln) * 1024 + qd * 8;
  short* bdst0 = &Bs[0][tg0 * 512 + l * 8];
  short* bdst1 = &Bs[0][tg1 * 512 + l * 8];

  f32x4 acc[8] = {};
  float4 a0[2], a1[2];
  s8v bn0, bn1;

  // tile 0 -> Bs[0]; tile 1 -> registers; A tiles 0,1 -> registers
  bn0 = *(const s8v*)(bsrc0);
  bn1 = *(const s8v*)(bsrc1);
  a0[0] = *(const float4*)(arow + 0);
  a1[0] = *(const float4*)(arow + 4);
  a0[1] = *(const float4*)(arow + 32);
  a1[1] = *(const float4*)(arow + 36);
  *(s8v*)bdst0 = bn0;
  *(s8v*)bdst1 = bn1;
  bn0 = *(const s8v*)(bsrc0 + 32);
  bn1 = *(const s8v*)(bsrc1 + 32);

  for (int kt = 0; kt < 32; ++kt) {
    const int cur = kt & 1;
    __syncthreads();   // orders reads(kt-1, buf cur^1) before writes(kt, buf cur^1)
    if (kt < 31) {
      *(s8v*)(bdst0 + (cur ^ 1) * 4096) = bn0;
      *(s8v*)(bdst1 + (cur ^ 1) * 4096) = bn1;
      if (kt < 30) {
        bn0 = *(const s8v*)(bsrc0 + (kt + 2) * 32);
        bn1 = *(const s8v*)(bsrc1 + (kt + 2) * 32);
      }
    }
    s8v af = { f2bf(a0[cur].x), f2bf(a0[cur].y), f2bf(a0[cur].z), f2bf(a0[cur].w),
               f2bf(a1[cur].x), f2bf(a1[cur].y), f2bf(a1[cur].z), f2bf(a1[cur].w) };
    if (kt < 30) {
      a0[cur] = *(const float4*)(arow + (kt + 2) * 32);
      a1[cur] = *(const float4*)(arow + (kt + 2) * 32 + 4);
    }
#pragma unroll
    for (int t = 0; t < 8; ++t) {
      s8v bf = *(const s8v*)&Bs[cur][t * 512 + l * 8];
      acc[t] = __builtin_amdgcn_mfma_f32_16x16x32_bf16(af, bf, acc[t], 0, 0, 0);
    }
  }
  // epilogue: bf16 z + per-row squared norms
#pragma unroll
  for (int p = 0; p < 4; ++p) {
    int grow = rb + w * 16 + qd * 4 + p;   // C/D: row = quad*4 + reg
    float sp = 0.0f;
#pragma unroll
    for (int t = 0; t < 8; ++t) {
      float v = acc[t][p];                 // col = t*16 + ln
      zb[(size_t)grow * 128 + t * 16 + ln] = (unsigned short)f2bf(v);
      sp += v * v;
    }
    sp += __shfl_xor(sp, 1);
    sp += __shfl_xor(sp, 2);
    sp += __shfl_xor(sp, 4);
    sp += __shfl_xor(sp, 8);
    if (ln == 0) n2[grow] = sp;
  }
}

// --------- fused d2 GEMM (64 queries x 256 protos) + per-class reduce ---------
__global__ __launch_bounds__(256, 1) void k_d2red(
    const unsigned short* __restrict__ zb, const float* __restrict__ n2,
    float* __restrict__ out) {
  __shared__ float Dt[256 * 65];          // Dt[j][q], stride 65 (bank-free)
  __shared__ float rv[256];
  __shared__ int   ri[256];
  __shared__ float rss[256];
  __shared__ float invn[64];
  __shared__ float sred[4];
  __shared__ float s_tc, s_aq2, s_corr;
  const int tid = threadIdx.x;
  const int c = blockIdx.x;
  const int w = tid >> 6, lane = tid & 63, ln = lane & 15, qd = lane >> 4;

  // d2 tile via MFMA: wave w handles query rows c*64 + w*16 .. +15
  f32x4 acc[16] = {};
  const unsigned short* Az = zb + (size_t)(256 + c * 64 + w * 16 + ln) * 128;
#pragma unroll
  for (int kt = 0; kt < 4; ++kt) {
    s8v af = *(const s8v*)(Az + kt * 32 + qd * 8);
#pragma unroll
    for (int t = 0; t < 16; ++t) {
      s8v bf = *(const s8v*)(zb + (size_t)(t * 16 + ln) * 128 + kt * 32 + qd * 8);
      acc[t] = __builtin_amdgcn_mfma_f32_16x16x32_bf16(af, bf, acc[t], 0, 0, 0);
    }
  }
#pragma unroll
  for (int p = 0; p < 4; ++p) {
    int qloc = w * 16 + qd * 4 + p;
    float qn = n2[256 + c * 64 + qloc];
#pragma unroll
    for (int t = 0; t < 16; ++t) {
      int j = t * 16 + ln;
      Dt[j * 65 + qloc] = qn + n2[j] - 2.0f * acc[t][p];
    }
  }
  __syncthreads();

  // per-row (query) stats: thread tid handles row q=tid&63, j-quarter (tid>>6)
  {
    const int q = tid & 63, jb = (tid >> 6) * 64;
    float mn = 3.4e38f; int mi = 0; float ss = 0.0f;
    for (int jj = 0; jj < 64; ++jj) {
      int j = jb + jj;
      float f = Dt[j * 65 + q];
      ss += f * f;
      if (f < mn) { mn = f; mi = j; }
    }
    rv[tid] = mn; ri[tid] = mi; rss[tid] = ss;
  }
  __syncthreads();
  if (tid < 64) {   // combine quarters; ascending h + strict < => first-occurrence
    float bm = rv[tid]; int bi = ri[tid]; float ss = rss[tid];
    for (int h = 1; h < 4; ++h) {
      float v = rv[h * 64 + tid];
      ss += rss[h * 64 + tid];
      if (v < bm) { bm = v; bi = ri[h * 64 + tid]; }
    }
    float col = Dt[c * 65 + tid];
    float loo2 = fmaxf(ss - col * col, 0.0f);
    float nrm = fmaxf(sqrtf(loo2), 1e-8f);
    float inv = 1.0f / nrm;
    invn[tid] = inv;
    float aq2 = loo2 * inv * inv;          // ||a_q||^2
    float corr = (bi == c) ? 1.0f : 0.0f;
    for (int m = 1; m < 64; m <<= 1) {
      aq2 += __shfl_xor(aq2, m);
      corr += __shfl_xor(corr, m);
    }
    if (tid == 0) { s_aq2 = aq2; s_corr = corr; }
  }
  __syncthreads();
  // t[j] = sum_q D[q][j] * invn[q]; thread tid = j
  float t = 0.0f;
  for (int qq = 0; qq < 64; ++qq) t += Dt[tid * 65 + qq] * invn[qq];
  if (tid == c) s_tc = t;
  float t2 = t * t;
  for (int m = 1; m < 64; m <<= 1) t2 += __shfl_xor(t2, m);
  if ((tid & 63) == 0) sred[tid >> 6] = t2;
  __syncthreads();
  if (tid == 0) {
    float S2 = sred[0] + sred[1] + sred[2] + sred[3];
    float bs = 0.5f * (S2 - s_tc * s_tc - s_aq2);   // sum_{q<k} sim
    atomicAdd(&out[0], bs * (1.0f / 516096.0f));    // / (C * Q*(Q-1)/2)
    atomicAdd(&out[1], s_corr * (1.0f / 16384.0f)); // / (C*Q)
  }
}

extern "C" void kernel_launch(void* const* d_in, const int* in_sizes, int n_in,
                              void* d_out, int out_size, void* d_ws, size_t ws_size,
                              hipStream_t stream) {
  const float* xs = (const float*)d_in[0];   // 256*5*1024
  const float* xq = (const float*)d_in[1];   // 256*64*1024
  const float* W  = (const float*)d_in[2];   // 1024*128
  float* out = (float*)d_out;

  float* ws = (float*)d_ws;
  float* xbar = ws;                                    // 262144 fp32 (1 MB)
  unsigned short* Wt = (unsigned short*)(xbar + 262144);          // 128K bf16
  unsigned short* zb = Wt + 131072;                               // 16640*128 bf16
  float* n2 = (float*)(zb + (size_t)16640 * 128);                 // 16640 fp32

  k_prep<<<dim3(272), dim3(256), 0, stream>>>(xs, W, xbar, Wt, out);
  k_gemm_z<<<dim3(260), dim3(256), 0, stream>>>(xbar, xq, Wt, zb, n2);
  k_d2red<<<dim3(256), dim3(256), 0, stream>>>(zb, n2, out);
}

// Round 5
// 141.056 us; speedup vs baseline: 1.4133x; 1.0251x over previous
//
#include <hip/hip_runtime.h>

// ProtoNet loss pipeline on MI355X (gfx950) — round 5.
// C=256 classes, S=5 support, Q=64 queries, D_IN=1024, Z=128.
//
// Round-5: k_gemm_z restructured for memory-level parallelism under the
// barrier-drain constraint (each __syncthreads emits s_waitcnt vmcnt(0),
// draining all global prefetches -> in-flight bytes = one barrier window).
//  - 512-thread blocks, 260 blocks -> 8 waves/CU (2/SIMD): TLP covers drains.
//  - In-block K-split: wave (rg = w>>1, h = w&1) does rows rg*16, K-half
//    h*512..+512. Halves summed via LDS in epilogue (no extra HBM traffic).
//  - BK=64 per barrier: in-flight/CU = A 32KB + B 32KB = 64KB (8x round 4).
// k_prep, k_d2red unchanged (controls).

typedef __attribute__((ext_vector_type(8))) short s8v;
typedef __attribute__((ext_vector_type(4))) float f32x4;

__device__ __forceinline__ short f2bf(float f) {
  union { float f; unsigned u; } v; v.f = f;
  unsigned r = (v.u + 0x7fffu + ((v.u >> 16) & 1u)) >> 16;   // RNE
  return (short)r;
}

// blocks 0..255: xbar[c,:] = mean_s xs[c,s,:]; block 0 also zeroes out[0..1].
// blocks 256..271: Wt[n][k] = bf16(W[k][n]) via LDS transpose (64 k-rows each).
__global__ __launch_bounds__(256) void k_prep(
    const float* __restrict__ xs, const float* __restrict__ W,
    float* __restrict__ xbar, unsigned short* __restrict__ Wt,
    float* __restrict__ out) {
  __shared__ unsigned short T[128 * 68];
  const int tid = threadIdx.x;
  if (blockIdx.x < 256) {
    const int c = blockIdx.x;
    if (c == 0 && tid < 2) out[tid] = 0.0f;
    const float* b = xs + (size_t)c * 5120;
    for (int e = tid; e < 1024; e += 256) {
      float s = b[e] + b[1024 + e] + b[2048 + e] + b[3072 + e] + b[4096 + e];
      xbar[(size_t)c * 1024 + e] = s * 0.2f;
    }
  } else {
    const int kb = (blockIdx.x - 256) * 64;
#pragma unroll
    for (int s = 0; s < 8; ++s) {          // 2048 float4 = 64 k x 32 n4
      int idx = tid + s * 256;
      int kr = idx >> 5, n4 = idx & 31;
      float4 v = *(const float4*)(W + (size_t)(kb + kr) * 128 + n4 * 4);
      T[(n4 * 4 + 0) * 68 + kr] = (unsigned short)f2bf(v.x);
      T[(n4 * 4 + 1) * 68 + kr] = (unsigned short)f2bf(v.y);
      T[(n4 * 4 + 2) * 68 + kr] = (unsigned short)f2bf(v.z);
      T[(n4 * 4 + 3) * 68 + kr] = (unsigned short)f2bf(v.w);
    }
    __syncthreads();
#pragma unroll
    for (int s = 0; s < 8; ++s) {          // 2048 ushort4 = 128 n x 16 k4
      int idx = tid + s * 256;
      int n = idx >> 4, k4 = idx & 15;
      ushort4 o;
      o.x = T[n * 68 + k4 * 4 + 0];
      o.y = T[n * 68 + k4 * 4 + 1];
      o.z = T[n * 68 + k4 * 4 + 2];
      o.w = T[n * 68 + k4 * 4 + 3];
      *(ushort4*)(Wt + (size_t)n * 1024 + kb + k4 * 4) = o;
    }
  }
}

// ---------------- z = [xbar ; xq] @ W,  M=16640 N=128 K=1024 ----------------
// 260 blocks x 512 threads. Wave w: rows rg*16 (rg=w>>1), K-half h (h=w&1).
// B double-buffered LDS [buf][half][sub][4096 shorts] = 64 KB total; epilogue
// aliases it as fp32 reduction buffer (stride 132 -> 2-way banks, free).
__global__ __launch_bounds__(512, 2) void k_gemm_z(
    const float* __restrict__ xbar, const float* __restrict__ xq,
    const unsigned short* __restrict__ Wt,
    unsigned short* __restrict__ zb, float* __restrict__ n2) {
  __shared__ short Bs[2][2][2][4096];     // [buf][half][sub][unit]
  const int tid = threadIdx.x;
  const int w = tid >> 6, l = tid & 63, ln = l & 15, qd = l >> 4;
  const int rg = w >> 1, h = w & 1;
  const int rb = blockIdx.x * 64;
  const float* abase = (rb < 256) ? (xbar + (size_t)rb * 1024)
                                  : (xq + (size_t)(rb - 256) * 1024);
  // lane's A stream: row rg*16+ln, k = h*512 + kt*64 + {qd*8, 32+qd*8}
  const float* arow = abase + (size_t)(rg * 16 + ln) * 1024 + h * 512 + qd * 8;
  // staging: thread tid stages unit tid of each (hh,ss) plane
  const int scol = ((tid >> 6) << 4) + (tid & 15);   // col 0..127
  const int sk8 = (tid >> 4) & 3;                    // k8 within 32-k sub
  const unsigned short* wsrc = Wt + (size_t)scol * 1024 + sk8 * 8;

  f32x4 acc[8] = {};
  s8v breg[4];
  float4 areg[2][4];

  // tile 0 -> Bs[0]; tile 1 -> breg; A tiles 0,1 -> areg
#pragma unroll
  for (int pl = 0; pl < 4; ++pl) {
    int hh = pl >> 1, ss = pl & 1;
    *(s8v*)&Bs[0][hh][ss][tid * 8] =
        *(const s8v*)(wsrc + hh * 512 + ss * 32);
  }
#pragma unroll
  for (int pl = 0; pl < 4; ++pl) {
    int hh = pl >> 1, ss = pl & 1;
    breg[pl] = *(const s8v*)(wsrc + hh * 512 + ss * 32 + 64);
  }
  areg[0][0] = *(const float4*)(arow + 0);
  areg[0][1] = *(const float4*)(arow + 4);
  areg[0][2] = *(const float4*)(arow + 32);
  areg[0][3] = *(const float4*)(arow + 36);
  areg[1][0] = *(const float4*)(arow + 64);
  areg[1][1] = *(const float4*)(arow + 68);
  areg[1][2] = *(const float4*)(arow + 96);
  areg[1][3] = *(const float4*)(arow + 100);

  for (int kt = 0; kt < 8; ++kt) {
    const int buf = kt & 1;
    __syncthreads();
    if (kt < 7) {
#pragma unroll
      for (int pl = 0; pl < 4; ++pl) {
        int hh = pl >> 1, ss = pl & 1;
        *(s8v*)&Bs[buf ^ 1][hh][ss][tid * 8] = breg[pl];
      }
      if (kt < 6) {
#pragma unroll
        for (int pl = 0; pl < 4; ++pl) {
          int hh = pl >> 1, ss = pl & 1;
          breg[pl] = *(const s8v*)(wsrc + hh * 512 + ss * 32 + (kt + 2) * 64);
        }
      }
    }
    s8v af0 = { f2bf(areg[buf][0].x), f2bf(areg[buf][0].y),
                f2bf(areg[buf][0].z), f2bf(areg[buf][0].w),
                f2bf(areg[buf][1].x), f2bf(areg[buf][1].y),
                f2bf(areg[buf][1].z), f2bf(areg[buf][1].w) };
    s8v af1 = { f2bf(areg[buf][2].x), f2bf(areg[buf][2].y),
                f2bf(areg[buf][2].z), f2bf(areg[buf][2].w),
                f2bf(areg[buf][3].x), f2bf(areg[buf][3].y),
                f2bf(areg[buf][3].z), f2bf(areg[buf][3].w) };
    if (kt < 6) {
      areg[buf][0] = *(const float4*)(arow + (kt + 2) * 64);
      areg[buf][1] = *(const float4*)(arow + (kt + 2) * 64 + 4);
      areg[buf][2] = *(const float4*)(arow + (kt + 2) * 64 + 32);
      areg[buf][3] = *(const float4*)(arow + (kt + 2) * 64 + 36);
    }
#pragma unroll
    for (int t = 0; t < 8; ++t) {
      s8v bf = *(const s8v*)&Bs[buf][h][0][t * 512 + l * 8];
      acc[t] = __builtin_amdgcn_mfma_f32_16x16x32_bf16(af0, bf, acc[t], 0, 0, 0);
    }
#pragma unroll
    for (int t = 0; t < 8; ++t) {
      s8v bf = *(const s8v*)&Bs[buf][h][1][t * 512 + l * 8];
      acc[t] = __builtin_amdgcn_mfma_f32_16x16x32_bf16(af1, bf, acc[t], 0, 0, 0);
    }
  }

  // ---- cross-half reduction via LDS alias, then epilogue by h==0 waves ----
  __syncthreads();                         // all Bs reads done
  float* R = (float*)&Bs[0][0][0][0];      // 4 rg x (16 rows x 132) fp32
  if (h == 1) {
#pragma unroll
    for (int p = 0; p < 4; ++p)
#pragma unroll
      for (int t = 0; t < 8; ++t)
        R[rg * 2112 + (qd * 4 + p) * 132 + t * 16 + ln] = acc[t][p];
  }
  __syncthreads();
  if (h == 0) {
#pragma unroll
    for (int p = 0; p < 4; ++p) {
      int grow = rb + rg * 16 + qd * 4 + p;   // C/D: row = quad*4 + reg
      float sp = 0.0f;
#pragma unroll
      for (int t = 0; t < 8; ++t) {
        float v = acc[t][p] + R[rg * 2112 + (qd * 4 + p) * 132 + t * 16 + ln];
        zb[(size_t)grow * 128 + t * 16 + ln] = (unsigned short)f2bf(v);
        sp += v * v;
      }
      sp += __shfl_xor(sp, 1);
      sp += __shfl_xor(sp, 2);
      sp += __shfl_xor(sp, 4);
      sp += __shfl_xor(sp, 8);
      if (ln == 0) n2[grow] = sp;
    }
  }
}

// --------- fused d2 GEMM (64 queries x 256 protos) + per-class reduce ---------
__global__ __launch_bounds__(256, 1) void k_d2red(
    const unsigned short* __restrict__ zb, const float* __restrict__ n2,
    float* __restrict__ out) {
  __shared__ float Dt[256 * 65];          // Dt[j][q], stride 65 (bank-free)
  __shared__ float rv[256];
  __shared__ int   ri[256];
  __shared__ float rss[256];
  __shared__ float invn[64];
  __shared__ float sred[4];
  __shared__ float s_tc, s_aq2, s_corr;
  const int tid = threadIdx.x;
  const int c = blockIdx.x;
  const int w = tid >> 6, lane = tid & 63, ln = lane & 15, qd = lane >> 4;

  // d2 tile via MFMA: wave w handles query rows c*64 + w*16 .. +15
  f32x4 acc[16] = {};
  const unsigned short* Az = zb + (size_t)(256 + c * 64 + w * 16 + ln) * 128;
#pragma unroll
  for (int kt = 0; kt < 4; ++kt) {
    s8v af = *(const s8v*)(Az + kt * 32 + qd * 8);
#pragma unroll
    for (int t = 0; t < 16; ++t) {
      s8v bf = *(const s8v*)(zb + (size_t)(t * 16 + ln) * 128 + kt * 32 + qd * 8);
      acc[t] = __builtin_amdgcn_mfma_f32_16x16x32_bf16(af, bf, acc[t], 0, 0, 0);
    }
  }
#pragma unroll
  for (int p = 0; p < 4; ++p) {
    int qloc = w * 16 + qd * 4 + p;
    float qn = n2[256 + c * 64 + qloc];
#pragma unroll
    for (int t = 0; t < 16; ++t) {
      int j = t * 16 + ln;
      Dt[j * 65 + qloc] = qn + n2[j] - 2.0f * acc[t][p];
    }
  }
  __syncthreads();

  // per-row (query) stats: thread tid handles row q=tid&63, j-quarter (tid>>6)
  {
    const int q = tid & 63, jb = (tid >> 6) * 64;
    float mn = 3.4e38f; int mi = 0; float ss = 0.0f;
    for (int jj = 0; jj < 64; ++jj) {
      int j = jb + jj;
      float f = Dt[j * 65 + q];
      ss += f * f;
      if (f < mn) { mn = f; mi = j; }
    }
    rv[tid] = mn; ri[tid] = mi; rss[tid] = ss;
  }
  __syncthreads();
  if (tid < 64) {   // combine quarters; ascending h + strict < => first-occurrence
    float bm = rv[tid]; int bi = ri[tid]; float ss = rss[tid];
    for (int hh = 1; hh < 4; ++hh) {
      float v = rv[hh * 64 + tid];
      ss += rss[hh * 64 + tid];
      if (v < bm) { bm = v; bi = ri[hh * 64 + tid]; }
    }
    float col = Dt[c * 65 + tid];
    float loo2 = fmaxf(ss - col * col, 0.0f);
    float nrm = fmaxf(sqrtf(loo2), 1e-8f);
    float inv = 1.0f / nrm;
    invn[tid] = inv;
    float aq2 = loo2 * inv * inv;          // ||a_q||^2
    float corr = (bi == c) ? 1.0f : 0.0f;
    for (int m = 1; m < 64; m <<= 1) {
      aq2 += __shfl_xor(aq2, m);
      corr += __shfl_xor(corr, m);
    }
    if (tid == 0) { s_aq2 = aq2; s_corr = corr; }
  }
  __syncthreads();
  // t[j] = sum_q D[q][j] * invn[q]; thread tid = j
  float t = 0.0f;
  for (int qq = 0; qq < 64; ++qq) t += Dt[tid * 65 + qq] * invn[qq];
  if (tid == c) s_tc = t;
  float t2 = t * t;
  for (int m = 1; m < 64; m <<= 1) t2 += __shfl_xor(t2, m);
  if ((tid & 63) == 0) sred[tid >> 6] = t2;
  __syncthreads();
  if (tid == 0) {
    float S2 = sred[0] + sred[1] + sred[2] + sred[3];
    float bs = 0.5f * (S2 - s_tc * s_tc - s_aq2);   // sum_{q<k} sim
    atomicAdd(&out[0], bs * (1.0f / 516096.0f));    // / (C * Q*(Q-1)/2)
    atomicAdd(&out[1], s_corr * (1.0f / 16384.0f)); // / (C*Q)
  }
}

extern "C" void kernel_launch(void* const* d_in, const int* in_sizes, int n_in,
                              void* d_out, int out_size, void* d_ws, size_t ws_size,
                              hipStream_t stream) {
  const float* xs = (const float*)d_in[0];   // 256*5*1024
  const float* xq = (const float*)d_in[1];   // 256*64*1024
  const float* W  = (const float*)d_in[2];   // 1024*128
  float* out = (float*)d_out;

  float* ws = (float*)d_ws;
  float* xbar = ws;                                    // 262144 fp32 (1 MB)
  unsigned short* Wt = (unsigned short*)(xbar + 262144);          // 128K bf16
  unsigned short* zb = Wt + 131072;                               // 16640*128 bf16
  float* n2 = (float*)(zb + (size_t)16640 * 128);                 // 16640 fp32

  k_prep<<<dim3(272), dim3(256), 0, stream>>>(xs, W, xbar, Wt, out);
  k_gemm_z<<<dim3(260), dim3(512), 0, stream>>>(xbar, xq, Wt, zb, n2);
  k_d2red<<<dim3(256), dim3(256), 0, stream>>>(zb, n2, out);
}